// Round 5
// baseline (1026.153 us; speedup 1.0000x reference)
//
#include <hip/hip_runtime.h>
#include <hip/hip_fp16.h>
#include <math.h>

// dims: T=128, B=64, V=100000, D=300, H=256
#define TSTEPS 128

typedef _Float16 half8 __attribute__((ext_vector_type(8)));
typedef float f32x4 __attribute__((ext_vector_type(4)));
typedef __attribute__((ext_vector_type(2))) _Float16 half2v;

#if __has_builtin(__builtin_amdgcn_fdot2)
#define FDOT2(a, b, c) __builtin_amdgcn_fdot2((a), (b), (c), false)
#else
static __device__ __forceinline__ float FDOT2(half2v a, half2v b, float c) {
    return c + (float)a.x * (float)b.x + (float)a.y * (float)b.y;
}
#endif

static __device__ __forceinline__ half2v h2(unsigned u) {
    union { unsigned x; half2v h; } t; t.x = u; return t.h;
}
static __device__ __forceinline__ unsigned packh2(float lo, float hi) {
    union { unsigned x; half2v h; } t; t.h.x = (_Float16)lo; t.h.y = (_Float16)hi; return t.x;
}
static __device__ __forceinline__ float sigm(float x) { return 1.0f / (1.0f + __expf(-x)); }
static __device__ __forceinline__ float tanh_(float x) { return 1.0f - 2.0f / (1.0f + __expf(2.0f * x)); }

template <int CTRL>
static __device__ __forceinline__ float qb(float v) {   // quad broadcast via DPP
    return __int_as_float(__builtin_amdgcn_update_dpp(0, __float_as_int(v), CTRL, 0xF, 0xF, true));
}

typedef __attribute__((address_space(1))) const unsigned GU;
typedef __attribute__((address_space(3))) unsigned LU;
static __device__ __forceinline__ void glds16(const void* g, void* l) {
    __builtin_amdgcn_global_load_lds((GU*)g, (LU*)(uintptr_t)l, 16, 0, 0);
}

// ---------------------------------------------------------------------------
// Kernel A: W_hh fp32[1024][256] -> W16T uint[128][1024] (half2-packed, k-pair major)
// ---------------------------------------------------------------------------
__global__ __launch_bounds__(256) void prep_whh(const float* __restrict__ Whh,
                                                unsigned* __restrict__ W16T) {
    __shared__ float tile[32][259];
    const int blk = blockIdx.x, tid = threadIdx.x;
#pragma unroll
    for (int l = 0; l < 32; ++l) {
        int idx = tid + l * 256;
        int r = idx >> 8, k = idx & 255;
        tile[r][k] = Whh[(size_t)(blk * 32 + r) * 256 + k];
    }
    __syncthreads();
#pragma unroll
    for (int l = 0; l < 16; ++l) {
        int o = tid + l * 256;
        int i = o >> 5, rl = o & 31;
        W16T[(size_t)i * 1024 + blk * 32 + rl] = packh2(tile[rl][2 * i], tile[rl][2 * i + 1]);
    }
}

// ---------------------------------------------------------------------------
// Fragment-major fp16 layouts for mfma_f32_16x16x32_f16.
// Granule (fr,ks), lane holds 8 halfs: row = fr*16+(lane&15);
// k = ks*32 + (lane>>4)*4 + {0..3} (c=0) and +16 (c=1).
// ---------------------------------------------------------------------------
// gather_x2: block fr stages 16 token rows in LDS (coalesced reads), writes
// the 10 granules (5 KB) linearly.
__global__ __launch_bounds__(256) void gather_x2(
    const int* __restrict__ s1, const int* __restrict__ s2,
    const float* __restrict__ emb, _Float16* __restrict__ xf)
{
    __shared__ float tile[16][301];
    __shared__ int toks[16];
    const int fr = blockIdx.x;                 // 0..1023
    const int tid = threadIdx.x;
    if (tid < 16) {
        const int m = fr * 16 + tid;
        toks[tid] = (m < 8192) ? s1[m] : s2[m - 8192];
    }
    __syncthreads();
#pragma unroll
    for (int l = 0; l < 19; ++l) {
        const int flat = tid + l * 256;        // 16*300 = 4800
        if (flat < 4800) {
            const int row = flat / 300, k = flat - row * 300;
            tile[row][k] = emb[(size_t)toks[row] * 300 + k];
        }
    }
    __syncthreads();
    unsigned* outp = (unsigned*)xf + (size_t)fr * 2560;
#pragma unroll
    for (int l = 0; l < 10; ++l) {
        const int d = tid + l * 256;           // 0..2559
        const int ks = d >> 8;
        const int rem = d & 255;
        const int lane = rem >> 2, ep = rem & 3;
        const int e0 = 2 * ep, c = e0 >> 2, j0 = e0 & 3;
        const int row = lane & 15;
        const int k = ks * 32 + (lane >> 4) * 4 + c * 16 + j0;
        const float f0 = (k < 300) ? tile[row][k] : 0.f;
        const float f1 = (k + 1 < 300) ? tile[row][k + 1] : 0.f;
        outp[d] = packh2(f0, f1);
    }
}

__global__ __launch_bounds__(256) void gather_w(
    const float* __restrict__ Wih, _Float16* __restrict__ wf)
{
    const int G = blockIdx.x * 256 + threadIdx.x;
    const int lane = G & 63;
    const int tmp = G >> 6;
    const int ks = tmp % 10;
    const int fr = tmp / 10;
    const int n = fr * 16 + (lane & 15);
    const float* row = Wih + (size_t)n * 300;
    const int k0 = ks * 32 + ((lane >> 4) & 3) * 4;
    half8 o;
#pragma unroll
    for (int c = 0; c < 2; ++c) {
        const int kc = k0 + c * 16;
#pragma unroll
        for (int j = 0; j < 4; ++j)
            o[c * 4 + j] = (_Float16)((kc + j < 300) ? row[kc + j] : 0.f);
    }
    *(half8*)(wf + (size_t)G * 8) = o;
}

// ---------------------------------------------------------------------------
// Kernel B: gx16 = x @ Wih^T (no bias), fp16 MFMA, 128x128 tile, dbuf LDS.
// ---------------------------------------------------------------------------
__global__ __launch_bounds__(256) void gx_gemm_mfma(
    const _Float16* __restrict__ xf, const _Float16* __restrict__ wf,
    _Float16* __restrict__ gx16)
{
    __shared__ _Float16 sm[2][8192];
    const int tid = threadIdx.x;
    const int lane = tid & 63, wv = tid >> 6;
    const int wr = wv >> 1, wc = wv & 1;
    const int bm = blockIdx.x & 127, bn = blockIdx.x >> 7;
    const int frM = bm * 8, frN = bn * 8;

    f32x4 acc[4][4] = {};

#define STAGE(buf, ks)                                                              \
    {                                                                               \
        _Pragma("unroll")                                                           \
        for (int i_ = 0; i_ < 2; ++i_) {                                            \
            const int fr_ = wv + 4 * i_;                                            \
            glds16(xf + (((size_t)(frM + fr_) * 10 + (ks)) * 64 + lane) * 8,        \
                   &sm[buf][fr_ * 512 + lane * 8]);                                 \
            glds16(wf + (((size_t)(frN + fr_) * 10 + (ks)) * 64 + lane) * 8,        \
                   &sm[buf][4096 + fr_ * 512 + lane * 8]);                          \
        }                                                                           \
    }

    STAGE(0, 0)
    for (int ks = 0; ks < 10; ++ks) {
        const int cur = ks & 1;
        if (ks < 9) {
            STAGE(cur ^ 1, ks + 1)
            asm volatile("s_waitcnt vmcnt(4)" ::: "memory");
        } else {
            asm volatile("s_waitcnt vmcnt(0)" ::: "memory");
        }
        __syncthreads();
        half8 av[4], bv[4];
#pragma unroll
        for (int i = 0; i < 4; ++i) {
            av[i] = *(const half8*)&sm[cur][(wr * 4 + i) * 512 + lane * 8];
            bv[i] = *(const half8*)&sm[cur][4096 + (wc * 4 + i) * 512 + lane * 8];
        }
#pragma unroll
        for (int i = 0; i < 4; ++i)
#pragma unroll
            for (int j = 0; j < 4; ++j)
                acc[i][j] = __builtin_amdgcn_mfma_f32_16x16x32_f16(av[i], bv[j], acc[i][j], 0, 0, 0);
        __syncthreads();
    }
#undef STAGE

    const int m0 = bm * 128 + wr * 64, n0 = bn * 128 + wc * 64;
    const int rl = ((lane >> 4) & 3) * 4, cl = lane & 15;
#pragma unroll
    for (int i = 0; i < 4; ++i)
#pragma unroll
        for (int j = 0; j < 4; ++j)
#pragma unroll
            for (int r = 0; r < 4; ++r)
                gx16[(size_t)(m0 + i * 16 + rl + r) * 1024 + n0 + j * 16 + cl] =
                    (_Float16)acc[i][j][r];
}

// ---------------------------------------------------------------------------
// Kernel C: recurrence. 256 blocks x 512 threads; chain = blk&127, hf = blk>>7.
// Thread (u = tid>>2, q = tid&3) owns gate-row r = q*256 + hf*128 + u with ALL
// 128 k-pair weights in VGPRs. Gate combine via DPP quad broadcast (redundant c
// per quad). Own-half h via double-buffered LDS; partner half via L2 exchange
// with monotonic flag handshake (agent scope). No per-step weight traffic.
// ---------------------------------------------------------------------------
__global__ __launch_bounds__(512, 2) void lstm_rec2(
    const unsigned* __restrict__ W16T,        // [128][1024] pair-major
    const unsigned short* __restrict__ gx16,  // [16384][1024] fp16 bits
    const float* __restrict__ bih, const float* __restrict__ bhh,
    const float* __restrict__ h0a, const float* __restrict__ c0a,
    const float* __restrict__ h0b, const float* __restrict__ c0b,
    unsigned* __restrict__ hx,                // [128 chain][2 buf][2 half][64] dwords
    unsigned* __restrict__ flags,             // [128][2] monotonic counters
    float* __restrict__ hfin)                 // [128][256]
{
    extern __shared__ unsigned smem[];        // 90112 B (occupancy pad); hbuf = first 128 dwords
    _Float16* hbuf = (_Float16*)smem;         // [2 buf][128 halfs]

    const int tid = threadIdx.x;
    const int chain = blockIdx.x & 127;
    const int hf = blockIdx.x >> 7;
    const int u = tid >> 2;                   // 0..127
    const int q = tid & 3;                    // gate i,f,g,o
    const int unit = hf * 128 + u;
    const int r = q * 256 + unit;

    // weights: own-half pairs then partner-half pairs, all VGPR
    unsigned wo[64], wp[64];
    const int ob = hf * 64, pb = (1 - hf) * 64;
#pragma unroll
    for (int i = 0; i < 64; ++i) wo[i] = W16T[(size_t)(ob + i) * 1024 + r];
#pragma unroll
    for (int i = 0; i < 64; ++i) wp[i] = W16T[(size_t)(pb + i) * 1024 + r];
#pragma unroll
    for (int i = 0; i < 64; ++i) {
        asm volatile("" : "+v"(wo[i]));
        asm volatile("" : "+v"(wp[i]));
    }

    const float bias = bih[r] + bhh[r];
    const int seq = chain >> 6, b = chain & 63;
    const float* h0 = seq ? h0b : h0a;
    const float* c0 = seq ? c0b : c0a;
    float c = c0[b * 256 + unit];
    const float h0v = h0[b * 256 + unit];

    // init: publish h(0) into buf0 (LDS + exchange), flag = 1, wait partner
    if (q == 0) {
        hbuf[u] = (_Float16)h0v;
        union { _Float16 f; unsigned short s; } cv; cv.f = (_Float16)h0v;
        ((unsigned short*)(hx + (((size_t)chain * 2 + 0) * 2 + hf) * 64))[u] = cv.s;
    }
    asm volatile("s_waitcnt vmcnt(0)" ::: "memory");
    __syncthreads();
    if (tid == 0) {
        __hip_atomic_store(&flags[chain * 2 + hf], 1u, __ATOMIC_RELEASE, __HIP_MEMORY_SCOPE_AGENT);
        while (__hip_atomic_load(&flags[chain * 2 + (1 - hf)], __ATOMIC_ACQUIRE,
                                 __HIP_MEMORY_SCOPE_AGENT) < 1u) {}
    }
    __syncthreads();

    const unsigned short* gxr = gx16 + ((size_t)seq * 8192 + b) * 1024 + r;

    for (int t = 0; t < TSTEPS; ++t) {
        const unsigned short gbits = gxr[(size_t)t * 65536];   // early issue
        const int buf = t & 1;

        // partner h loads (L2, same-address broadcast) — issued before own crunch
        const uint4* php = (const uint4*)(hx + (((size_t)chain * 2 + buf) * 2 + (1 - hf)) * 64);
        uint4 ph[16];
#pragma unroll
        for (int j = 0; j < 16; ++j) ph[j] = php[j];

        // own-half FDOT2 (LDS broadcasts) while partner loads fly
        const uint4* hop = (const uint4*)(smem + buf * 64);
        float a0 = 0.f, a1 = 0.f, a2 = 0.f, a3 = 0.f;
#pragma unroll
        for (int j = 0; j < 16; ++j) {
            const uint4 hv = hop[j];
            a0 = FDOT2(h2(wo[4 * j + 0]), h2(hv.x), a0);
            a1 = FDOT2(h2(wo[4 * j + 1]), h2(hv.y), a1);
            a2 = FDOT2(h2(wo[4 * j + 2]), h2(hv.z), a2);
            a3 = FDOT2(h2(wo[4 * j + 3]), h2(hv.w), a3);
        }
#pragma unroll
        for (int j = 0; j < 16; ++j) {
            a0 = FDOT2(h2(wp[4 * j + 0]), h2(ph[j].x), a0);
            a1 = FDOT2(h2(wp[4 * j + 1]), h2(ph[j].y), a1);
            a2 = FDOT2(h2(wp[4 * j + 2]), h2(ph[j].z), a2);
            a3 = FDOT2(h2(wp[4 * j + 3]), h2(ph[j].w), a3);
        }
        const float pre = ((a0 + a1) + (a2 + a3)) + (float)*(const _Float16*)&gbits + bias;

        // activation: g uses tanh = 2*sigm(2x)-1 -> single exp for all gates
        const bool isg = (q == 2);
        const float xs = isg ? 2.f * pre : pre;
        const float ev = __expf(-xs);
        const float vv = 1.f / (1.f + ev);
        const float act = isg ? 2.f * vv - 1.f : vv;

        // quad broadcast of the 4 gate activations; redundant c per quad lane
        const float gi = qb<0x00>(act);
        const float gf = qb<0x55>(act);
        const float gg = qb<0xAA>(act);
        const float go = qb<0xFF>(act);
        c = fmaf(gf, c, gi * gg);
        const float h = go * tanh_(c);

        // publish h(t+1) into buf^1
        if (q == 0) {
            hbuf[(buf ^ 1) * 128 + u] = (_Float16)h;
            if (t < TSTEPS - 1) {
                union { _Float16 f; unsigned short s; } cv; cv.f = (_Float16)h;
                ((unsigned short*)(hx + (((size_t)chain * 2 + (buf ^ 1)) * 2 + hf) * 64))[u] = cv.s;
            } else {
                hfin[(size_t)chain * 256 + unit] = h;
            }
        }
        if (t < TSTEPS - 1) {
            asm volatile("s_waitcnt vmcnt(0)" ::: "memory");   // wave-local store drain
            __syncthreads();                                   // all waves drained
            if (tid == 0) {
                __hip_atomic_store(&flags[chain * 2 + hf], (unsigned)(t + 2),
                                   __ATOMIC_RELEASE, __HIP_MEMORY_SCOPE_AGENT);
                while (__hip_atomic_load(&flags[chain * 2 + (1 - hf)], __ATOMIC_ACQUIRE,
                                         __HIP_MEMORY_SCOPE_AGENT) < (unsigned)(t + 2)) {}
            }
            __syncthreads();
        }
    }
}

// ---------------------------------------------------------------------------
// Kernel D: y[b] = clip(exp(-sum_u |hA - hB|))
// ---------------------------------------------------------------------------
__global__ __launch_bounds__(256) void final_norm(const float* __restrict__ hfin,
                                                  float* __restrict__ out) {
    __shared__ float ws[4];
    const int b = blockIdx.x, tid = threadIdx.x;
    float d = fabsf(hfin[(size_t)b * 256 + tid] - hfin[(size_t)(64 + b) * 256 + tid]);
#pragma unroll
    for (int off = 32; off; off >>= 1) d += __shfl_down(d, off);
    if ((tid & 63) == 0) ws[tid >> 6] = d;
    __syncthreads();
    if (tid == 0) {
        float n = ws[0] + ws[1] + ws[2] + ws[3];
        float y = expf(-n);
        y = fminf(fmaxf(y, 1e-7f), 1.0f - 1e-7f);
        out[b] = y;
    }
}

// ---------------------------------------------------------------------------
// Workspace:
//   xf    @ 0         : 16384*320 fp16            (10,485,760 B)
//   wf    @ 10485760  : 1024*320 fp16             (655,360 B)
//   gx16  @ 16 MB     : 16384*1024 fp16           (33,554,432 B)
//   W16T  @ 50331648  : 512 KB
//   hfin  @ 50855936  : 128 KB
//   hx    @ 50987008  : 128 KB (h exchange)
//   flags @ 51118080  : 4 KB (memset 0)
// ---------------------------------------------------------------------------
extern "C" void kernel_launch(void* const* d_in, const int* in_sizes, int n_in,
                              void* d_out, int out_size, void* d_ws, size_t ws_size,
                              hipStream_t stream) {
    const int*   s1  = (const int*)d_in[0];
    const int*   s2  = (const int*)d_in[1];
    const float* emb = (const float*)d_in[2];
    const float* Wih = (const float*)d_in[3];
    const float* Whh = (const float*)d_in[4];
    const float* bih = (const float*)d_in[5];
    const float* bhh = (const float*)d_in[6];
    const float* h0a = (const float*)d_in[7];
    const float* c0a = (const float*)d_in[8];
    const float* h0b = (const float*)d_in[9];
    const float* c0b = (const float*)d_in[10];
    float* out = (float*)d_out;

    char* ws = (char*)d_ws;
    _Float16* xf    = (_Float16*)ws;
    _Float16* wfp   = (_Float16*)(ws + 10485760);
    _Float16* gx16  = (_Float16*)(ws + (size_t)16 * 1024 * 1024);
    unsigned* W16T  = (unsigned*)(ws + 50331648);
    float*    hfin  = (float*)(ws + 50855936);
    unsigned* hx    = (unsigned*)(ws + 50987008);
    unsigned* flags = (unsigned*)(ws + 51118080);

    hipMemsetAsync(flags, 0, 4096, stream);

    prep_whh<<<32, 256, 0, stream>>>(Whh, W16T);
    gather_x2<<<1024, 256, 0, stream>>>(s1, s2, emb, xf);
    gather_w<<<160, 256, 0, stream>>>(Wih, wfp);
    gx_gemm_mfma<<<1024, 256, 0, stream>>>(xf, wfp, gx16);

    lstm_rec2<<<256, 512, 90112, stream>>>(W16T, (const unsigned short*)gx16,
                                           bih, bhh, h0a, c0a, h0b, c0b,
                                           hx, flags, hfin);
    final_norm<<<64, 256, 0, stream>>>(hfin, out);
}